// Round 11
// baseline (35.549 us; speedup 1.0000x reference)
//
#include <hip/hip_runtime.h>

#define TPB 512
#define PER_THREAD 32
#define CHUNK (TPB * PER_THREAD)     // 16384 elements per block
#define WCHUNK (64 * PER_THREAD)     // 2048 elements per wave
#define NQ 8                         // float4 loads per lane per wave

// ---------------------------------------------------------------------------
// Exclusive block-wide scan of one unsigned per thread (tid order).
// ---------------------------------------------------------------------------
__device__ __forceinline__ unsigned block_excl_scan(unsigned tsum, unsigned* wtot) {
    const int lane = threadIdx.x & 63;
    const int wid  = threadIdx.x >> 6;
    unsigned v = tsum;
#pragma unroll
    for (int off = 1; off < 64; off <<= 1) {
        unsigned u = __shfl_up(v, off, 64);
        if (lane >= off) v += u;
    }
    if (lane == 63) wtot[wid] = v;
    __syncthreads();
    unsigned woff = 0;
    for (int w = 0; w < wid; ++w) woff += wtot[w];
    return woff + v - tsum;   // exclusive prefix for this thread
}

// ---------------------------------------------------------------------------
// Pass 1: wave-coalesced score read. Grouped-4 load issue (short live
// ranges: 4 float4 in flight, consumed immediately after the group —
// r8 lesson: depth-8 across the prelude killed occupancy; r10 lesson:
// prelude itself is not the limiter).
// Mask word g covers elements [32g, 32g+32) in global element order.
// ---------------------------------------------------------------------------
__global__ void k_count(const float* __restrict__ score,
                        unsigned* __restrict__ blockCount,
                        unsigned* __restrict__ mask, long n) {
    const int  tid  = threadIdx.x;
    const int  lane = tid & 63, w = tid >> 6;
    const long base  = (long)blockIdx.x * CHUNK;
    const long wbase = base + (long)w * WCHUNK;
    unsigned cnt = 0;

    auto proc = [&](int q, const float4& v) {
        unsigned nib = (unsigned)(v.x > 0.f)        | ((unsigned)(v.y > 0.f) << 1)
                     | ((unsigned)(v.z > 0.f) << 2) | ((unsigned)(v.w > 0.f) << 3);
        cnt += __popc(nib);
        unsigned part = nib << ((lane & 7) * 4);
        part |= __shfl_xor(part, 1);
        part |= __shfl_xor(part, 2);
        part |= __shfl_xor(part, 4);
        if ((lane & 7) == 0 && mask)
            mask[(wbase >> 5) + 8 * q + (lane >> 3)] = part;
    };

    if (base + CHUNK <= n) {
        const float4* s4 = reinterpret_cast<const float4*>(score);
        const long ib = wbase / 4 + lane;
#pragma unroll
        for (int g = 0; g < NQ / 4; ++g) {
            float4 v0 = s4[ib + 64 * (4 * g + 0)];   // 4 loads in flight
            float4 v1 = s4[ib + 64 * (4 * g + 1)];
            float4 v2 = s4[ib + 64 * (4 * g + 2)];
            float4 v3 = s4[ib + 64 * (4 * g + 3)];
            proc(4 * g + 0, v0);
            proc(4 * g + 1, v1);
            proc(4 * g + 2, v2);
            proc(4 * g + 3, v3);
        }
    } else {
        for (int q = 0; q < NQ; ++q) {
            unsigned nib = 0;
#pragma unroll
            for (int j = 0; j < 4; ++j) {
                long gi = wbase + 256 * q + 4 * lane + j;
                if (gi < n && score[gi] > 0.f) nib |= (1u << j);
            }
            cnt += __popc(nib);
            unsigned part = nib << ((lane & 7) * 4);
            part |= __shfl_xor(part, 1);
            part |= __shfl_xor(part, 2);
            part |= __shfl_xor(part, 4);
            if ((lane & 7) == 0 && mask)
                mask[(wbase >> 5) + 8 * q + (lane >> 3)] = part;
        }
    }

#pragma unroll
    for (int off = 32; off > 0; off >>= 1) cnt += __shfl_down(cnt, off, 64);
    __shared__ unsigned wsum[TPB / 64];
    if (lane == 0) wsum[w] = cnt;
    __syncthreads();
    if (tid == 0) {
        unsigned tot = 0;
        for (int i = 0; i < TPB / 64; ++i) tot += wsum[i];
        blockCount[blockIdx.x] = tot;
    }
}

// ---------------------------------------------------------------------------
// Pass 2: round-10 proven scheme, with grouped-4 predict load issue in the
// full path. Math/rank path byte-identical to rounds 7/10 (absmax 0.0).
// No fences, no atomics (r3/5/6); no long live ranges (r8); no math
// rewrites (r9).
// ---------------------------------------------------------------------------
template <bool USE_MASK>
__global__ void k_main(const float* __restrict__ predict,
                       const float* __restrict__ score,
                       const unsigned* __restrict__ mask,
                       const unsigned* __restrict__ blockCount,
                       double* __restrict__ blockSum, long n, int B) {
    const int  tid  = threadIdx.x;
    const int  bid  = blockIdx.x;
    const int  lane = tid & 63, w = tid >> 6;
    const long base  = (long)bid * CHUNK;
    const long wbase = base + (long)w * WCHUNK;
    const bool full  = (base + CHUNK <= n);

    __shared__ unsigned wtot[TPB / 64];
    __shared__ unsigned wpart[2 * (TPB / 64)];
    __shared__ unsigned s_off, s_P;
    __shared__ double   dsum[TPB / 64];

    // --- this thread's mask word (its 32 contiguous elements) ---
    unsigned wd = 0;
    if (USE_MASK) {
        wd = mask[(size_t)bid * TPB + tid];
    } else {
        const long tb = base + (long)tid * PER_THREAD;
        if (tb + PER_THREAD <= n) {
            const float4* s4 = reinterpret_cast<const float4*>(score + tb);
#pragma unroll
            for (int q = 0; q < PER_THREAD / 4; ++q) {
                float4 v = s4[q];
                wd |= ((unsigned)(v.x > 0.f)) << (4 * q + 0);
                wd |= ((unsigned)(v.y > 0.f)) << (4 * q + 1);
                wd |= ((unsigned)(v.z > 0.f)) << (4 * q + 2);
                wd |= ((unsigned)(v.w > 0.f)) << (4 * q + 3);
            }
        } else {
            for (int e = 0; e < PER_THREAD; ++e) {
                long gi = tb + e;
                if (gi < n && score[gi] > 0.f) wd |= (1u << e);
            }
        }
    }

    unsigned cnt  = __popc(wd);
    unsigned excl = block_excl_scan(cnt, wtot);

    // --- per-block exclusive offset + global total P from blockCount ---
    unsigned offp = 0, tot = 0;
    for (int j = tid; j < B; j += TPB) {
        unsigned c = blockCount[j];
        tot  += c;
        offp += (j < bid) ? c : 0u;
    }
#pragma unroll
    for (int off = 32; off > 0; off >>= 1) {
        offp += __shfl_down(offp, off, 64);
        tot  += __shfl_down(tot,  off, 64);
    }
    if (lane == 0) { wpart[2 * w] = offp; wpart[2 * w + 1] = tot; }
    __syncthreads();
    if (tid == 0) {
        unsigned o = 0, t = 0;
        for (int i = 0; i < TPB / 64; ++i) { o += wpart[2 * i]; t += wpart[2 * i + 1]; }
        s_off = o; s_P = t;
    }
    __syncthreads();

    const unsigned P = s_P;
    const float invS = 1.0f / (float)P;                 // s value at positives
    const float sumS = (float)((double)invS * (double)P);
    const float rcpSumS = 1.0f / sumS;
    const float Pf = (float)P;

    const unsigned pre = s_off + excl;   // positives before this thread's word

    double acc = 0.0;
    if (full) {
        const float4* p4 = reinterpret_cast<const float4*>(predict);
        const long ib = wbase / 4 + lane;

        auto proc = [&](int q, const float4& cur) {
            const int t = 8 * q + (lane >> 3);
            const unsigned wq  = __shfl(wd,  t, 64);
            const unsigned prq = __shfl(pre, t, 64);
            const int nibStart = (lane & 7) * 4;
            unsigned run = prq + __popc(wq & ((1u << nibStart) - 1u));
            const unsigned nib = (wq >> nibStart) & 0xFu;
            const float pv[4] = {cur.x, cur.y, cur.z, cur.w};
#pragma unroll
            for (int j = 0; j < 4; ++j) {
                const bool ispos = (nib >> j) & 1u;
                const unsigned newrun = run + (ispos ? 1u : 0u);
                const long gi = wbase + 256 * q + 4 * lane + j;
                const float p = pv[j] * rcpSumS;
                const float kp1  = (float)(newrun + 1u);
                const float posv = p * __builtin_amdgcn_rcpf(kp1)
                                 - invS * __builtin_amdgcn_rcpf(__log2f(kp1));
                const unsigned mr = (unsigned)(gi + 1) - newrun;
                const float negv  = p * __builtin_amdgcn_rcpf(Pf + (float)mr + 1.0f);
                const float tt = ispos ? posv : negv;
                acc += (double)(tt * tt);
                run = newrun;
            }
        };

#pragma unroll
        for (int g = 0; g < NQ / 4; ++g) {
            float4 c0 = p4[ib + 64 * (4 * g + 0)];   // 4 loads in flight
            float4 c1 = p4[ib + 64 * (4 * g + 1)];
            float4 c2 = p4[ib + 64 * (4 * g + 2)];
            float4 c3 = p4[ib + 64 * (4 * g + 3)];
            proc(4 * g + 0, c0);
            proc(4 * g + 1, c1);
            proc(4 * g + 2, c2);
            proc(4 * g + 3, c3);
        }
    } else {
        for (int q = 0; q < NQ; ++q) {
            const int t = 8 * q + (lane >> 3);
            const unsigned wq  = __shfl(wd,  t, 64);
            const unsigned prq = __shfl(pre, t, 64);
            const int nibStart = (lane & 7) * 4;
            unsigned run = prq + __popc(wq & ((1u << nibStart) - 1u));
            const unsigned nib = (wq >> nibStart) & 0xFu;
            for (int j = 0; j < 4; ++j) {
                const long gi = wbase + 256 * q + 4 * lane + j;
                if (gi >= n) continue;
                const bool ispos = (nib >> j) & 1u;
                const unsigned newrun = run + (ispos ? 1u : 0u);
                const float p = predict[gi] * rcpSumS;
                const float kp1  = (float)(newrun + 1u);
                const float posv = p * __builtin_amdgcn_rcpf(kp1)
                                 - invS * __builtin_amdgcn_rcpf(__log2f(kp1));
                const unsigned mr = (unsigned)(gi + 1) - newrun;
                const float negv  = p * __builtin_amdgcn_rcpf(Pf + (float)mr + 1.0f);
                const float tt = ispos ? posv : negv;
                acc += (double)(tt * tt);
                run = newrun;
            }
        }
    }

    // --- deterministic block reduce ---
#pragma unroll
    for (int off = 32; off > 0; off >>= 1) acc += __shfl_down(acc, off, 64);
    if (lane == 0) dsum[w] = acc;
    __syncthreads();
    if (tid == 0) {
        double t = 0.0;
        for (int i = 0; i < TPB / 64; ++i) t += dsum[i];
        blockSum[bid] = t;
    }
}

// ---------------------------------------------------------------------------
// Pass 3: deterministic reduce of per-block doubles -> float scalar.
// ---------------------------------------------------------------------------
__global__ void k_final(const double* __restrict__ blockSum,
                        float* __restrict__ out, int B) {
    const int tid = threadIdx.x;
    double acc = 0.0;
    for (int j = tid; j < B; j += TPB) acc += blockSum[j];
#pragma unroll
    for (int off = 32; off > 0; off >>= 1) acc += __shfl_down(acc, off, 64);
    __shared__ double dsum[TPB / 64];
    const int lane = tid & 63, wid = tid >> 6;
    if (lane == 0) dsum[wid] = acc;
    __syncthreads();
    if (tid == 0) {
        double tot = 0.0;
        for (int w = 0; w < TPB / 64; ++w) tot += dsum[w];
        out[0] = (float)tot;
    }
}

extern "C" void kernel_launch(void* const* d_in, const int* in_sizes, int n_in,
                              void* d_out, int out_size, void* d_ws, size_t ws_size,
                              hipStream_t stream) {
    const float* predict = (const float*)d_in[0];
    const float* score   = (const float*)d_in[1];
    const long n = (long)in_sizes[0];
    const int B = (int)((n + CHUNK - 1) / CHUNK);   // 1024 for N=2^24

    unsigned char* ws = (unsigned char*)d_ws;
    size_t off = 0;
    unsigned* blockCount = (unsigned*)(ws + off); off += (size_t)B * sizeof(unsigned);
    off = (off + 255) & ~(size_t)255;
    double*   blockSum   = (double*)(ws + off);   off += (size_t)B * sizeof(double);
    off = (off + 255) & ~(size_t)255;
    unsigned* maskBuf    = (unsigned*)(ws + off);
    const size_t maskBytes = (size_t)B * TPB * sizeof(unsigned);
    const bool useMask = (off + maskBytes) <= ws_size;

    k_count<<<B, TPB, 0, stream>>>(score, blockCount, useMask ? maskBuf : nullptr, n);
    if (useMask)
        k_main<true><<<B, TPB, 0, stream>>>(predict, nullptr, maskBuf, blockCount,
                                            blockSum, n, B);
    else
        k_main<false><<<B, TPB, 0, stream>>>(predict, score, nullptr, blockCount,
                                             blockSum, n, B);
    k_final<<<1, TPB, 0, stream>>>(blockSum, (float*)d_out, B);
}